// Round 4
// baseline (6901.146 us; speedup 1.0000x reference)
//
#include <hip/hip_runtime.h>
#include <math.h>

#define NROWS   32768
#define EDIM    512
#define NE      1024
#define NLAYERS 4
#define FLAT_CAP 524288u

// ---- ws offsets (bytes), total ~71.7 MB ----
#define OFF_RES    0           // 64 MB residual
#define OFF_KEYS   67108864    // 4 layers * 32768 * u64 = 1 MB
#define OFF_FLAG   68157440    // 4 * 32768 * u32 = 512 KB
#define OFF_FLAT   68681728    // 524288 u32 entries = 2 MB
#define OFF_CBBF   70778880    // 4096*512 bf16 = 4 MB
#define OFF_A      74973184    // 32768 f32
#define OFF_B      75104256    // 4096 f32
#define OFF_MAXB   75120640    // 4 f32 (+pad)
#define OFF_LOSS   75120704    // 4 dbl
#define OFF_CNT    75120736    // 4096 int
#define OFF_FLATC  75137120    // 4 u32
#define ZERO_SPAN  16432       // OFF_LOSS..end of FLATC

typedef __attribute__((ext_vector_type(8))) short bf16x8;
typedef __attribute__((ext_vector_type(4))) float f32x4;

// round-to-nearest-even f32 -> bf16 (deterministic, bound-friendly)
__device__ __forceinline__ unsigned short f2bf(float f) {
    unsigned u = __float_as_uint(f);
    unsigned r = ((u >> 16) & 1u) + 0x7FFFu;
    return (unsigned short)((u + r) >> 16);
}

__device__ __forceinline__ void gload_lds16(const void* g, void* l) {
    __builtin_amdgcn_global_load_lds(
        (const __attribute__((address_space(1))) unsigned int*)g,
        (__attribute__((address_space(3))) unsigned int*)l, 16, 0, 0);
}

__device__ __forceinline__ unsigned long long dkey(float d, int code) {
    unsigned u = __float_as_uint(d);
    u ^= (u & 0x80000000u) ? 0xFFFFFFFFu : 0x80000000u;
    return ((unsigned long long)u << 32) | (unsigned)code;
}

// ---------------------------------------------------------------------------
// numpy-pairwise f32 sum of squares per row (n=512), optional bf16 copy out.
__global__ __launch_bounds__(256) void pairsum_kernel(const float* __restrict__ src,
                                                      float* __restrict__ dst,
                                                      unsigned short* __restrict__ bfout) {
    __shared__ float buf[4][EDIM];
    const int tid = threadIdx.x, lane = tid & 63, w = tid >> 6;
    const int row = blockIdx.x * 4 + w;
    const float4* s4 = reinterpret_cast<const float4*>(src + (size_t)row * EDIM);
    float4 a = s4[lane * 2], b = s4[lane * 2 + 1];
    if (bfout) {
        unsigned short u[8] = {f2bf(a.x), f2bf(a.y), f2bf(a.z), f2bf(a.w),
                               f2bf(b.x), f2bf(b.y), f2bf(b.z), f2bf(b.w)};
        *reinterpret_cast<uint4*>(bfout + (size_t)row * EDIM + lane * 8) =
            *reinterpret_cast<const uint4*>(u);
    }
    float* br = buf[w];
    br[lane*8+0]=a.x; br[lane*8+1]=a.y; br[lane*8+2]=a.z; br[lane*8+3]=a.w;
    br[lane*8+4]=b.x; br[lane*8+5]=b.y; br[lane*8+6]=b.z; br[lane*8+7]=b.w;
    __syncthreads();
    if (lane < 32) {
        const int bb = lane >> 3, j = lane & 7;
        const float* p = &br[128 * bb + j];
        float v = p[0];
        float r = __fmul_rn(v, v);
        #pragma unroll
        for (int i = 1; i < 16; ++i) { v = p[8 * i]; r = __fadd_rn(r, __fmul_rn(v, v)); }
        r = __fadd_rn(r, __shfl_xor(r, 1));
        r = __fadd_rn(r, __shfl_xor(r, 2));
        r = __fadd_rn(r, __shfl_xor(r, 4));
        r = __fadd_rn(r, __shfl_xor(r, 8));
        r = __fadd_rn(r, __shfl_xor(r, 16));
        if (lane == 0) dst[row] = r;
    }
}

// ---------------------------------------------------------------------------
__global__ __launch_bounds__(256) void maxb_kernel(const float* __restrict__ Bn,
                                                   float* __restrict__ maxb) {
    __shared__ float red[256];
    int tid = threadIdx.x;
    for (int l = 0; l < NLAYERS; ++l) {
        float m = fmaxf(fmaxf(Bn[l*NE + tid], Bn[l*NE + 256 + tid]),
                        fmaxf(Bn[l*NE + 512 + tid], Bn[l*NE + 768 + tid]));
        red[tid] = m; __syncthreads();
        for (int s = 128; s > 0; s >>= 1) {
            if (tid < s) red[tid] = fmaxf(red[tid], red[tid + s]);
            __syncthreads();
        }
        if (tid == 0) maxb[l] = red[0];
        __syncthreads();
    }
}

// ---------------------------------------------------------------------------
// bf16 MFMA distance GEMM + candidate selection for one layer.
// Block: 64 rows x all 1024 codes, K-step 64, 16 waves (2 Mw x 8 Nw),
// wave strip 32 rows x 128 cols, 16x16x32 MFMA, acc 2x8 f32x4.
// LDS tiles 128 B/row with byte ^= ((row&7)<<4) swizzle (2-way = free).
__global__ __launch_bounds__(1024, 4) void gemm_argmin_kernel(
        const float* __restrict__ resin,
        const unsigned short* __restrict__ cbbf,   // this layer, [1024][512] bf16
        const float* __restrict__ An,
        const float* __restrict__ Bn,              // this layer, [1024]
        const float* __restrict__ maxbp,           // this layer scalar
        unsigned* __restrict__ flat,
        unsigned* __restrict__ flatcnt,
        unsigned* __restrict__ rowflag) {          // this layer, [32768]
    __shared__ unsigned short Bs[NE * 64];     // 128 KB
    __shared__ unsigned short As[64 * 64];     // 8 KB
    __shared__ float nA[64];
    __shared__ float nB[NE];
    __shared__ float minbuf[64][8];
    __shared__ float rowthr[64];
    __shared__ int   rowcnt[64];

    const int tid = threadIdx.x;
    const int lane = tid & 63;
    const int wid = tid >> 6;
    const int mw = wid >> 3;
    const int nw = wid & 7;
    const int row0 = blockIdx.x * 64;

    if (tid < 64) { nA[tid] = An[row0 + tid]; rowcnt[tid] = 0; }
    nB[tid] = Bn[tid];
    const float maxbv = maxbp[0];

    f32x4 acc[2][8];
    #pragma unroll
    for (int i = 0; i < 2; ++i)
        #pragma unroll
        for (int j = 0; j < 8; ++j) acc[i][j] = (f32x4){0.f, 0.f, 0.f, 0.f};

    for (int t = 0; t < 8; ++t) {
        __syncthreads();
        // stage B tile: 1024 codes x 64 k bf16 via global_load_lds (linear LDS,
        // inverse-swizzled global source)
        {
            const int cb0 = wid * 8;
            #pragma unroll
            for (int i = 0; i < 8; ++i) {
                int ldsbyte = (cb0 + i) * 1024 + lane * 16;
                int code = ldsbyte >> 7;
                int kbp  = ldsbyte & 127;
                int kbl  = kbp ^ ((code & 7) << 4);
                gload_lds16(cbbf + (size_t)code * EDIM + t * 64 + (kbl >> 1),
                            (char*)Bs + ldsbyte);
            }
        }
        // stage A tile: 64 rows x 64 k, f32 -> bf16, swizzled ds_write
        {
            int r  = tid >> 4;
            int k4 = (tid & 15) * 4;
            float4 v = *reinterpret_cast<const float4*>(
                resin + (size_t)(row0 + r) * EDIM + t * 64 + k4);
            uint2 p;
            p.x = (unsigned)f2bf(v.x) | ((unsigned)f2bf(v.y) << 16);
            p.y = (unsigned)f2bf(v.z) | ((unsigned)f2bf(v.w) << 16);
            int off = r * 128 + ((k4 * 2) ^ ((r & 7) << 4));
            *reinterpret_cast<uint2*>((char*)As + off) = p;
        }
        __syncthreads();
        #pragma unroll
        for (int kk = 0; kk < 2; ++kk) {
            const int b = kk * 64 + (lane >> 4) * 16;
            bf16x8 a0, a1;
            {
                int rl = mw * 32 + (lane & 15);
                a0 = *reinterpret_cast<const bf16x8*>((const char*)As + rl * 128 + (b ^ ((rl & 7) << 4)));
                rl += 16;
                a1 = *reinterpret_cast<const bf16x8*>((const char*)As + rl * 128 + (b ^ ((rl & 7) << 4)));
            }
            #pragma unroll
            for (int nf = 0; nf < 8; ++nf) {
                int cl = nw * 128 + nf * 16 + (lane & 15);
                bf16x8 bb = *reinterpret_cast<const bf16x8*>((const char*)Bs + cl * 128 + (b ^ ((cl & 7) << 4)));
                acc[0][nf] = __builtin_amdgcn_mfma_f32_16x16x32_bf16(a0, bb, acc[0][nf], 0, 0, 0);
                acc[1][nf] = __builtin_amdgcn_mfma_f32_16x16x32_bf16(a1, bb, acc[1][nf], 0, 0, 0);
            }
        }
    }

    // ---- epilogue: per-row approx min, threshold, candidate append ----
    float dmin[2][4];
    #pragma unroll
    for (int mf = 0; mf < 2; ++mf)
        #pragma unroll
        for (int j = 0; j < 4; ++j) {
            int rl = mw * 32 + mf * 16 + (lane >> 4) * 4 + j;
            float av = nA[rl];
            float m = 1e30f;
            #pragma unroll
            for (int nf = 0; nf < 8; ++nf) {
                int cl = nw * 128 + nf * 16 + (lane & 15);
                float d = (av + nB[cl]) - 2.0f * acc[mf][nf][j];
                m = fminf(m, d);
            }
            dmin[mf][j] = m;
        }
    #pragma unroll
    for (int off = 1; off <= 8; off <<= 1)
        #pragma unroll
        for (int mf = 0; mf < 2; ++mf)
            #pragma unroll
            for (int j = 0; j < 4; ++j)
                dmin[mf][j] = fminf(dmin[mf][j], __shfl_xor(dmin[mf][j], off));
    if ((lane & 15) == 0) {
        #pragma unroll
        for (int mf = 0; mf < 2; ++mf)
            #pragma unroll
            for (int j = 0; j < 4; ++j)
                minbuf[mw * 32 + mf * 16 + (lane >> 4) * 4 + j][nw] = dmin[mf][j];
    }
    __syncthreads();
    if (tid < 64) {
        float m = minbuf[tid][0];
        #pragma unroll
        for (int q = 1; q < 8; ++q) m = fminf(m, minbuf[tid][q]);
        // hard error bound: 2*(2^-6 * sqrt(A*Bmax)) * 1.25 + 1e-3 slack
        rowthr[tid] = m + (0.0390625f * sqrtf(nA[tid] * maxbv) + 1e-3f);
    }
    __syncthreads();
    #pragma unroll
    for (int mf = 0; mf < 2; ++mf)
        #pragma unroll
        for (int j = 0; j < 4; ++j) {
            int rl = mw * 32 + mf * 16 + (lane >> 4) * 4 + j;
            float av = nA[rl], th = rowthr[rl];
            #pragma unroll
            for (int nf = 0; nf < 8; ++nf) {
                int cl = nw * 128 + nf * 16 + (lane & 15);
                float d = (av + nB[cl]) - 2.0f * acc[mf][nf][j];
                if (d <= th) {
                    int slot = atomicAdd(&rowcnt[rl], 1);
                    if (slot < 64) {
                        unsigned pos = atomicAdd(flatcnt, 1u);
                        if (pos < FLAT_CAP) flat[pos] = ((unsigned)(row0 + rl) << 10) | (unsigned)cl;
                        else rowflag[row0 + rl] = 1u;
                    } else {
                        rowflag[row0 + rl] = 1u;
                    }
                }
            }
        }
}

// ---------------------------------------------------------------------------
// Exact f32-chain recheck of flat candidate list; atomicMin packed (d, code).
__global__ __launch_bounds__(256) void recheck_kernel(const float* __restrict__ rin,
                                                      const float* __restrict__ cbl,
                                                      const float* __restrict__ An,
                                                      const float* __restrict__ Bn,
                                                      const unsigned* __restrict__ flat,
                                                      const unsigned* __restrict__ flatcnt,
                                                      unsigned long long* __restrict__ keys) {
    unsigned total = flatcnt[0];
    if (total > FLAT_CAP) total = FLAT_CAP;
    const int lane = threadIdx.x & 63;
    const unsigned wave = blockIdx.x * 4 + (threadIdx.x >> 6);
    const unsigned nw = gridDim.x * 4;
    for (unsigned base = wave * 64; base < total; base += nw * 64) {
        unsigned e = base + lane;
        bool act = e < total;
        unsigned v = act ? flat[e] : 0u;
        int row = v >> 10, code = v & 1023;
        const float4* zr = reinterpret_cast<const float4*>(rin + (size_t)row * EDIM);
        const float4* cr = reinterpret_cast<const float4*>(cbl + (size_t)code * EDIM);
        float s = 0.f;
        #pragma unroll 8
        for (int q = 0; q < 128; ++q) {
            float4 z4 = zr[q], c4 = cr[q];
            s = fmaf(2.0f * z4.x, c4.x, s); s = fmaf(2.0f * z4.y, c4.y, s);
            s = fmaf(2.0f * z4.z, c4.z, s); s = fmaf(2.0f * z4.w, c4.w, s);
        }
        float d = __fsub_rn(__fadd_rn(An[row], Bn[code]), s);
        if (act) atomicMin(&keys[row], dkey(d, code));
    }
}

// ---------------------------------------------------------------------------
// Full exact scan for overflow-flagged rows (normally none).
__global__ __launch_bounds__(256) void fallback_kernel(const float* __restrict__ rin,
                                                       const float* __restrict__ cbl,
                                                       const float* __restrict__ An,
                                                       const float* __restrict__ Bn,
                                                       const unsigned* __restrict__ flag,
                                                       unsigned long long* __restrict__ keys) {
    const int wid = blockIdx.x * 4 + (threadIdx.x >> 6);
    const int lane = threadIdx.x & 63;
    for (int row = wid; row < NROWS; row += 2048) {
        if (flag[row] == 0u) continue;
        const float4* zr = reinterpret_cast<const float4*>(rin + (size_t)row * EDIM);
        float Av = An[row];
        unsigned long long best = 0xFFFFFFFFFFFFFFFFull;
        for (int i = 0; i < 16; ++i) {
            int code = i * 64 + lane;
            const float4* cr = reinterpret_cast<const float4*>(cbl + (size_t)code * EDIM);
            float s = 0.f;
            #pragma unroll 8
            for (int q = 0; q < 128; ++q) {
                float4 z4 = zr[q], c4 = cr[q];
                s = fmaf(2.0f * z4.x, c4.x, s); s = fmaf(2.0f * z4.y, c4.y, s);
                s = fmaf(2.0f * z4.z, c4.z, s); s = fmaf(2.0f * z4.w, c4.w, s);
            }
            float d = __fsub_rn(__fadd_rn(Av, Bn[code]), s);
            unsigned long long k = dkey(d, code);
            best = (k < best) ? k : best;
        }
        for (int off = 32; off > 0; off >>= 1) {
            unsigned long long o = __shfl_xor(best, off);
            best = (o < best) ? o : best;
        }
        if (lane == 0) atomicMin(&keys[row], best);
    }
}

// ---------------------------------------------------------------------------
// Residual update + loss SSE + histogram + index-as-float; code from keys.
__global__ __launch_bounds__(256) void update_kernel(const float* resin, float* resout,
                                                     const float* __restrict__ cb,
                                                     const unsigned long long* __restrict__ keys,
                                                     double* __restrict__ lossacc,
                                                     int* __restrict__ counts,
                                                     float* __restrict__ idxf) {
    int tid  = threadIdx.x;
    int lane = tid & 63;
    int waveg = blockIdx.x * 4 + (tid >> 6);
    double lpart = 0.0;
    for (int row = waveg; row < NROWS; row += 1024) {
        int code = (int)(keys[row] & 1023ull);
        const float4* rin  = reinterpret_cast<const float4*>(resin + (size_t)row * EDIM);
        const float4* cin  = reinterpret_cast<const float4*>(cb + (size_t)code * EDIM);
        float4*       rout = reinterpret_cast<float4*>(resout + (size_t)row * EDIM);
        #pragma unroll
        for (int j = 0; j < 2; ++j) {
            float4 r = rin[lane + 64 * j];
            float4 c = cin[lane + 64 * j];
            float4 o = make_float4(r.x - c.x, r.y - c.y, r.z - c.z, r.w - c.w);
            rout[lane + 64 * j] = o;
            lpart += (double)o.x * o.x + (double)o.y * o.y
                   + (double)o.z * o.z + (double)o.w * o.w;
        }
        if (lane == 0) {
            atomicAdd(&counts[code], 1);
            idxf[row] = (float)code;
        }
    }
    __shared__ double red[256];
    red[tid] = lpart;
    __syncthreads();
    for (int s = 128; s > 0; s >>= 1) {
        if (tid < s) red[tid] += red[tid + s];
        __syncthreads();
    }
    if (tid == 0) atomicAdd(lossacc, red[0]);
}

// ---------------------------------------------------------------------------
__global__ __launch_bounds__(256) void zqsum_kernel(const float* __restrict__ z,
                                                    const float* __restrict__ res,
                                                    float* __restrict__ outz) {
    size_t i4 = (size_t)blockIdx.x * 256 + threadIdx.x;
    const float4* z4 = reinterpret_cast<const float4*>(z);
    const float4* r4 = reinterpret_cast<const float4*>(res);
    float4 zv = z4[i4];
    float4 rv = r4[i4];
    size_t b = i4 * 4;
    outz[b + 0] = zv.x - rv.x;
    outz[b + 1] = zv.y - rv.y;
    outz[b + 2] = zv.z - rv.z;
    outz[b + 3] = zv.w - rv.w;
}

// ---------------------------------------------------------------------------
__global__ __launch_bounds__(256) void finalize_kernel(const double* __restrict__ lossacc,
                                                       const int* __restrict__ counts,
                                                       float* __restrict__ out_loss,
                                                       float* __restrict__ out_perp) {
    __shared__ double red[256];
    int tid = threadIdx.x;
    if (tid == 0) {
        double t = 0.25 * (lossacc[0] + lossacc[1] + lossacc[2] + lossacc[3]) / 16777216.0;
        out_loss[0] = (float)t;
    }
    for (int l = 0; l < NLAYERS; ++l) {
        double s = 0.0;
        for (int c = tid; c < NE; c += 256) {
            double p = counts[l * NE + c] * (1.0 / 32768.0);
            s += p * log(p + 1e-10);
        }
        red[tid] = s;
        __syncthreads();
        for (int st = 128; st > 0; st >>= 1) {
            if (tid < st) red[tid] += red[tid + st];
            __syncthreads();
        }
        if (tid == 0) out_perp[l] = (float)exp(-red[0]);
        __syncthreads();
    }
}

// ---------------------------------------------------------------------------
extern "C" void kernel_launch(void* const* d_in, const int* in_sizes, int n_in,
                              void* d_out, int out_size, void* d_ws, size_t ws_size,
                              hipStream_t stream) {
    const float* z  = (const float*)d_in[0];
    const float* cb = (const float*)d_in[1];
    float* out  = (float*)d_out;
    float* outz = out + 1;
    float* idxf = out + 1 + 16777216;
    float* perp = out + 1 + 16777216 + 131072;

    char* ws = (char*)d_ws;
    float*              res     = (float*)(ws + OFF_RES);
    unsigned long long* keys    = (unsigned long long*)(ws + OFF_KEYS);
    unsigned*           rowflag = (unsigned*)(ws + OFF_FLAG);
    unsigned*           flat    = (unsigned*)(ws + OFF_FLAT);
    unsigned short*     cbbf    = (unsigned short*)(ws + OFF_CBBF);
    float*              Aws     = (float*)(ws + OFF_A);
    float*              Bws     = (float*)(ws + OFF_B);
    float*              maxb    = (float*)(ws + OFF_MAXB);
    double*             lossacc = (double*)(ws + OFF_LOSS);
    int*                counts  = (int*)(ws + OFF_CNT);
    unsigned*           flatcnt = (unsigned*)(ws + OFF_FLATC);

    hipMemsetAsync(ws + OFF_LOSS, 0, ZERO_SPAN, stream);          // loss+counts+flatcnt
    hipMemsetAsync(ws + OFF_FLAG, 0, NLAYERS * NROWS * 4, stream);
    hipMemsetAsync(ws + OFF_KEYS, 0xFF, NLAYERS * NROWS * 8, stream);

    pairsum_kernel<<<1024, 256, 0, stream>>>(cb, Bws, cbbf);      // 4096 cb rows + bf16
    maxb_kernel<<<1, 256, 0, stream>>>(Bws, maxb);

    for (int l = 0; l < NLAYERS; ++l) {
        const float* rin = (l == 0) ? z : res;
        const float* cbl = cb + (size_t)l * NE * EDIM;
        pairsum_kernel<<<8192, 256, 0, stream>>>(rin, Aws, nullptr);
        gemm_argmin_kernel<<<512, 1024, 0, stream>>>(rin,
                                                     cbbf + (size_t)l * NE * EDIM,
                                                     Aws, Bws + l * NE, maxb + l,
                                                     flat, flatcnt + l,
                                                     rowflag + l * NROWS);
        recheck_kernel<<<1024, 256, 0, stream>>>(rin, cbl, Aws, Bws + l * NE,
                                                 flat, flatcnt + l, keys + (size_t)l * NROWS);
        fallback_kernel<<<512, 256, 0, stream>>>(rin, cbl, Aws, Bws + l * NE,
                                                 rowflag + l * NROWS, keys + (size_t)l * NROWS);
        update_kernel<<<256, 256, 0, stream>>>(rin, res, cbl, keys + (size_t)l * NROWS,
                                               lossacc + l, counts + l * NE,
                                               idxf + l * NROWS);
    }
    zqsum_kernel<<<16384, 256, 0, stream>>>(z, res, outz);
    finalize_kernel<<<1, 256, 0, stream>>>(lossacc, counts, out, perp);
}

// Round 5
// 2273.524 us; speedup vs baseline: 3.0354x; 3.0354x over previous
//
#include <hip/hip_runtime.h>
#include <math.h>

#define NROWS   32768
#define EDIM    512
#define NE      1024
#define NLAYERS 4

// ---- ws offsets (bytes), total ~72 MB (<= 75 MB proven available) ----
#define OFF_RES   0ull          // 64 MB residual f32
#define OFF_CBBF  67108864ull   // 4096*512 bf16 = 4 MB
#define OFF_A     71303168ull   // 32768 f32 row norms
#define OFF_B     71434240ull   // 4096 f32 codebook norms
#define OFF_MAXB  71450624ull   // 4 f32 + pad
#define OFF_LOSS  71450688ull   // 4 dbl
#define OFF_CNT   71450720ull   // 4096 int
#define OFF_IDX   71467104ull   // 4*32768 int

typedef __attribute__((ext_vector_type(8))) short bf16x8;
typedef __attribute__((ext_vector_type(4))) float f32x4;

__device__ __forceinline__ unsigned f2bf(float f) {
    unsigned u = __float_as_uint(f);
    unsigned r = ((u >> 16) & 1u) + 0x7FFFu;
    return (u + r) >> 16;
}

__device__ __forceinline__ void gload_lds16(const void* g, void* l) {
    __builtin_amdgcn_global_load_lds(
        (const __attribute__((address_space(1))) unsigned int*)g,
        (__attribute__((address_space(3))) unsigned int*)l, 16, 0, 0);
}

__device__ __forceinline__ unsigned long long dkey(float d, int code) {
    unsigned u = __float_as_uint(d);
    u ^= (u & 0x80000000u) ? 0xFFFFFFFFu : 0x80000000u;
    return ((unsigned long long)u << 32) | (unsigned)code;
}

// ---------------------------------------------------------------------------
// numpy-pairwise f32 sum of squares per row (n=512); optional bf16 copy out.
__global__ __launch_bounds__(256) void pairsum_kernel(const float* __restrict__ src,
                                                      float* __restrict__ dst,
                                                      unsigned short* __restrict__ bfout) {
    __shared__ float buf[4][EDIM];
    const int tid = threadIdx.x, lane = tid & 63, w = tid >> 6;
    const int row = blockIdx.x * 4 + w;
    const float4* s4 = reinterpret_cast<const float4*>(src + (size_t)row * EDIM);
    float4 a = s4[lane * 2], b = s4[lane * 2 + 1];
    if (bfout) {
        unsigned p[4];
        p[0] = f2bf(a.x) | (f2bf(a.y) << 16);
        p[1] = f2bf(a.z) | (f2bf(a.w) << 16);
        p[2] = f2bf(b.x) | (f2bf(b.y) << 16);
        p[3] = f2bf(b.z) | (f2bf(b.w) << 16);
        *reinterpret_cast<uint4*>(bfout + (size_t)row * EDIM + lane * 8) =
            *reinterpret_cast<const uint4*>(p);
    }
    float* br = buf[w];
    br[lane*8+0]=a.x; br[lane*8+1]=a.y; br[lane*8+2]=a.z; br[lane*8+3]=a.w;
    br[lane*8+4]=b.x; br[lane*8+5]=b.y; br[lane*8+6]=b.z; br[lane*8+7]=b.w;
    __syncthreads();
    if (lane < 32) {
        const int bb = lane >> 3, j = lane & 7;
        const float* p = &br[128 * bb + j];
        float v = p[0];
        float r = __fmul_rn(v, v);
        #pragma unroll
        for (int i = 1; i < 16; ++i) { v = p[8 * i]; r = __fadd_rn(r, __fmul_rn(v, v)); }
        r = __fadd_rn(r, __shfl_xor(r, 1));
        r = __fadd_rn(r, __shfl_xor(r, 2));
        r = __fadd_rn(r, __shfl_xor(r, 4));
        r = __fadd_rn(r, __shfl_xor(r, 8));
        r = __fadd_rn(r, __shfl_xor(r, 16));
        if (lane == 0) dst[row] = r;
    }
}

// ---------------------------------------------------------------------------
__global__ __launch_bounds__(256) void maxb_kernel(const float* __restrict__ Bn,
                                                   float* __restrict__ maxb) {
    __shared__ float red[256];
    int tid = threadIdx.x;
    for (int l = 0; l < NLAYERS; ++l) {
        float m = fmaxf(fmaxf(Bn[l*NE + tid], Bn[l*NE + 256 + tid]),
                        fmaxf(Bn[l*NE + 512 + tid], Bn[l*NE + 768 + tid]));
        red[tid] = m; __syncthreads();
        for (int s = 128; s > 0; s >>= 1) {
            if (tid < s) red[tid] = fmaxf(red[tid], red[tid + s]);
            __syncthreads();
        }
        if (tid == 0) maxb[l] = red[0];
        __syncthreads();
    }
}

// ---------------------------------------------------------------------------
// m97-style bf16 MFMA GEMM: 128x128 tile, BK=64, 512 thr (8 waves, 2Mw x 4Nw),
// 32 KB LDS (linear, no swizzle), B via global_load_lds, A reg-staged f32->bf16.
// Emits d_rel = Bn[col] - 2*dot as fp16 to drel[row][1024] (row stride 2048 B).
__global__ __launch_bounds__(512) void gemm_dist_kernel(
        const float* __restrict__ resin,
        const unsigned short* __restrict__ cbbf,   // layer codebook bf16
        const float* __restrict__ Bn,              // layer [1024]
        char* __restrict__ drel) {                 // base 8B-aligned
    __shared__ char smem[32768];
    unsigned short* As = (unsigned short*)smem;            // [128][64]
    unsigned short* Bs = (unsigned short*)(smem + 16384);  // [128][64]
    const int tid = threadIdx.x, lane = tid & 63, wid = tid >> 6;
    const int mw = wid >> 2, nw = wid & 3;
    const int mt = blockIdx.x & 255, nt = blockIdx.x >> 8;  // same-XCD A sharing
    const int row0 = mt * 128, nc0 = nt * 128;

    f32x4 acc[4][2];
    #pragma unroll
    for (int fr = 0; fr < 4; ++fr)
        #pragma unroll
        for (int fc = 0; fc < 2; ++fc) acc[fr][fc] = (f32x4){0.f,0.f,0.f,0.f};

    const int arow = tid >> 2;            // 0..127
    const int akq  = (tid & 3) << 4;      // 0,16,32,48
    const float* aptr = resin + (size_t)(row0 + arow) * EDIM + akq;

    for (int t = 0; t < 8; ++t) {
        __syncthreads();
        // B: 16 KB via 2 linear gload_lds chunks (lane-contiguous, coalesced)
        #pragma unroll
        for (int c = 0; c < 2; ++c) {
            int byteo = c * 8192 + tid * 16;
            int code  = byteo >> 7;
            int kel   = (byteo & 127) >> 1;
            gload_lds16(cbbf + (size_t)(nc0 + code) * EDIM + t * 64 + kel,
                        (char*)Bs + byteo);
        }
        // A: 64B f32 per thread -> 16 bf16 -> 32B ds_write
        {
            const float* ap = aptr + t * 64;
            float4 w0 = *reinterpret_cast<const float4*>(ap);
            float4 w1 = *reinterpret_cast<const float4*>(ap + 4);
            float4 w2 = *reinterpret_cast<const float4*>(ap + 8);
            float4 w3 = *reinterpret_cast<const float4*>(ap + 12);
            unsigned p[8];
            p[0] = f2bf(w0.x) | (f2bf(w0.y) << 16);
            p[1] = f2bf(w0.z) | (f2bf(w0.w) << 16);
            p[2] = f2bf(w1.x) | (f2bf(w1.y) << 16);
            p[3] = f2bf(w1.z) | (f2bf(w1.w) << 16);
            p[4] = f2bf(w2.x) | (f2bf(w2.y) << 16);
            p[5] = f2bf(w2.z) | (f2bf(w2.w) << 16);
            p[6] = f2bf(w3.x) | (f2bf(w3.y) << 16);
            p[7] = f2bf(w3.z) | (f2bf(w3.w) << 16);
            char* adst = (char*)As + arow * 128 + akq * 2;
            *reinterpret_cast<uint4*>(adst)      = *reinterpret_cast<const uint4*>(p);
            *reinterpret_cast<uint4*>(adst + 16) = *reinterpret_cast<const uint4*>(p + 4);
        }
        __syncthreads();
        #pragma unroll
        for (int kk = 0; kk < 2; ++kk) {
            bf16x8 af[4], bfv[2];
            #pragma unroll
            for (int fr = 0; fr < 4; ++fr)
                af[fr] = *reinterpret_cast<const bf16x8*>(
                    (const char*)As + (mw*64 + fr*16 + (lane&15))*128 + kk*64 + (lane>>4)*16);
            #pragma unroll
            for (int fc = 0; fc < 2; ++fc)
                bfv[fc] = *reinterpret_cast<const bf16x8*>(
                    (const char*)Bs + (nw*32 + fc*16 + (lane&15))*128 + kk*64 + (lane>>4)*16);
            #pragma unroll
            for (int fr = 0; fr < 4; ++fr)
                #pragma unroll
                for (int fc = 0; fc < 2; ++fc)
                    acc[fr][fc] = __builtin_amdgcn_mfma_f32_16x16x32_bf16(
                        af[fr], bfv[fc], acc[fr][fc], 0, 0, 0);
        }
    }

    // epilogue: d_rel = Bn - 2*acc, fp16, repack via LDS for coalesced stores
    float bnv[2];
    bnv[0] = Bn[nc0 + nw*32 + (lane & 15)];
    bnv[1] = Bn[nc0 + nw*32 + 16 + (lane & 15)];
    __syncthreads();
    _Float16* Cs = (_Float16*)smem;   // [128][128]
    #pragma unroll
    for (int fr = 0; fr < 4; ++fr)
        #pragma unroll
        for (int fc = 0; fc < 2; ++fc)
            #pragma unroll
            for (int j = 0; j < 4; ++j) {
                int r = mw*64 + fr*16 + (lane >> 4)*4 + j;
                int cl = nw*32 + fc*16 + (lane & 15);
                Cs[r*128 + cl] = (_Float16)(bnv[fc] - 2.0f * acc[fr][fc][j]);
            }
    __syncthreads();
    const int srow = tid >> 2, spart = tid & 3;
    const char* csrc = smem + srow * 256 + spart * 64;
    char* cdst = drel + (size_t)(row0 + srow) * 2048 + nc0 * 2 + spart * 64;
    #pragma unroll
    for (int q = 0; q < 8; ++q)
        *reinterpret_cast<uint2*>(cdst + q*8) = *reinterpret_cast<const uint2*>(csrc + q*8);
}

// ---------------------------------------------------------------------------
// Per-row: fp16 d_rel scan -> min+margin -> exact f32-chain recheck of
// candidates -> lexicographic (d,code) min (= np.argmin) -> fused update.
__global__ __launch_bounds__(256) void rowscan_kernel(
        const float* __restrict__ rin, float* __restrict__ resout,
        const float* __restrict__ cbl,
        const char* __restrict__ drel,
        const float* __restrict__ An, const float* __restrict__ Bn,
        const float* __restrict__ maxbp,
        double* __restrict__ lossacc, int* __restrict__ counts,
        int* __restrict__ idxbuf) {
    __shared__ float rs[4][EDIM];
    __shared__ unsigned short cand[4][NE];
    __shared__ int cnt[4];
    const int tid = threadIdx.x, lane = tid & 63, w = tid >> 6;
    const int row = blockIdx.x * 4 + w;
    if (lane == 0) cnt[w] = 0;

    const float4* rp = reinterpret_cast<const float4*>(rin + (size_t)row * EDIM);
    float4 z0 = rp[lane*2], z1 = rp[lane*2 + 1];
    *reinterpret_cast<float4*>(&rs[w][lane*8])     = z0;
    *reinterpret_cast<float4*>(&rs[w][lane*8 + 4]) = z1;

    const uint2* dp = reinterpret_cast<const uint2*>(drel + (size_t)row * 2048);
    float dv[16];
    #pragma unroll
    for (int q = 0; q < 4; ++q) {
        uint2 du = dp[lane*4 + q];
        const _Float16* hh = reinterpret_cast<const _Float16*>(&du);
        dv[q*4+0] = (float)hh[0]; dv[q*4+1] = (float)hh[1];
        dv[q*4+2] = (float)hh[2]; dv[q*4+3] = (float)hh[3];
    }
    float m = dv[0];
    #pragma unroll
    for (int q = 1; q < 16; ++q) m = fminf(m, dv[q]);
    #pragma unroll
    for (int off = 1; off <= 32; off <<= 1) m = fminf(m, __shfl_xor(m, off));
    const float Av = An[row];
    const float thr = m + 0.03f * sqrtf(Av * maxbp[0]) + 2e-3f;
    __syncthreads();
    #pragma unroll
    for (int q = 0; q < 16; ++q)
        if (dv[q] <= thr) {
            int slot = atomicAdd(&cnt[w], 1);
            cand[w][slot] = (unsigned short)(lane*16 + q);
        }
    __syncthreads();
    const int ncand = cnt[w];

    unsigned long long best = 0xFFFFFFFFFFFFFFFFull;
    for (int base = 0; base < ncand; base += 64) {
        int ci = base + lane;
        if (ci < ncand) {
            int code = cand[w][ci];
            const float4* cp = reinterpret_cast<const float4*>(cbl + (size_t)code * EDIM);
            float s = 0.f;
            #pragma unroll 8
            for (int q = 0; q < 128; ++q) {
                float4 c4 = cp[q];
                float4 z4 = *reinterpret_cast<const float4*>(&rs[w][q*4]);
                s = fmaf(2.0f*z4.x, c4.x, s); s = fmaf(2.0f*z4.y, c4.y, s);
                s = fmaf(2.0f*z4.z, c4.z, s); s = fmaf(2.0f*z4.w, c4.w, s);
            }
            float d = __fsub_rn(__fadd_rn(Av, Bn[code]), s);
            unsigned long long k = dkey(d, code);
            if (k < best) best = k;
        }
    }
    #pragma unroll
    for (int off = 1; off <= 32; off <<= 1) {
        unsigned long long o = __shfl_xor(best, off);
        if (o < best) best = o;
    }
    const int bc = (int)(best & 1023ull);

    // fused residual update + loss + histogram + index
    const float4* cp = reinterpret_cast<const float4*>(cbl + (size_t)bc * EDIM);
    float4 c0 = cp[lane*2], c1 = cp[lane*2 + 1];
    float4 o0 = make_float4(z0.x - c0.x, z0.y - c0.y, z0.z - c0.z, z0.w - c0.w);
    float4 o1 = make_float4(z1.x - c1.x, z1.y - c1.y, z1.z - c1.z, z1.w - c1.w);
    float4* rout = reinterpret_cast<float4*>(resout + (size_t)row * EDIM);
    rout[lane*2] = o0; rout[lane*2 + 1] = o1;
    double lp = (double)o0.x*o0.x + (double)o0.y*o0.y + (double)o0.z*o0.z + (double)o0.w*o0.w
              + (double)o1.x*o1.x + (double)o1.y*o1.y + (double)o1.z*o1.z + (double)o1.w*o1.w;
    #pragma unroll
    for (int off = 1; off <= 32; off <<= 1) lp += __shfl_xor(lp, off);
    if (lane == 0) {
        atomicAdd(lossacc, lp);
        atomicAdd(&counts[bc], 1);
        idxbuf[row] = bc;
    }
}

// ---------------------------------------------------------------------------
__global__ __launch_bounds__(256) void zqsum_kernel(const float* __restrict__ z,
                                                    const float* __restrict__ res,
                                                    float* __restrict__ outz) {
    size_t i4 = (size_t)blockIdx.x * 256 + threadIdx.x;
    const float4* z4 = reinterpret_cast<const float4*>(z);
    const float4* r4 = reinterpret_cast<const float4*>(res);
    float4 zv = z4[i4];
    float4 rv = r4[i4];
    size_t b = i4 * 4;
    outz[b + 0] = zv.x - rv.x;
    outz[b + 1] = zv.y - rv.y;
    outz[b + 2] = zv.z - rv.z;
    outz[b + 3] = zv.w - rv.w;
}

// ---------------------------------------------------------------------------
__global__ __launch_bounds__(256) void writeidx_kernel(const int* __restrict__ idxbuf,
                                                       float* __restrict__ idxf) {
    int i = blockIdx.x * 256 + threadIdx.x;
    idxf[i] = (float)idxbuf[i];
}

// ---------------------------------------------------------------------------
__global__ __launch_bounds__(256) void finalize_kernel(const double* __restrict__ lossacc,
                                                       const int* __restrict__ counts,
                                                       float* __restrict__ out_loss,
                                                       float* __restrict__ out_perp) {
    __shared__ double red[256];
    int tid = threadIdx.x;
    if (tid == 0) {
        double t = 0.25 * (lossacc[0] + lossacc[1] + lossacc[2] + lossacc[3]) / 16777216.0;
        out_loss[0] = (float)t;
    }
    for (int l = 0; l < NLAYERS; ++l) {
        double s = 0.0;
        for (int c = tid; c < NE; c += 256) {
            double p = counts[l * NE + c] * (1.0 / 32768.0);
            s += p * log(p + 1e-10);
        }
        red[tid] = s;
        __syncthreads();
        for (int st = 128; st > 0; st >>= 1) {
            if (tid < st) red[tid] += red[tid + st];
            __syncthreads();
        }
        if (tid == 0) out_perp[l] = (float)exp(-red[0]);
        __syncthreads();
    }
}

// ---------------------------------------------------------------------------
extern "C" void kernel_launch(void* const* d_in, const int* in_sizes, int n_in,
                              void* d_out, int out_size, void* d_ws, size_t ws_size,
                              hipStream_t stream) {
    const float* z  = (const float*)d_in[0];
    const float* cb = (const float*)d_in[1];
    float* out  = (float*)d_out;
    float* outz = out + 1;
    float* idxf = out + 1 + 16777216;
    float* perp = out + 1 + 16777216 + 131072;
    char*  drelbase = (char*)d_out + 8;   // 8B-aligned fp16 D region (dead z_q space)

    char* ws = (char*)d_ws;
    float*          res     = (float*)(ws + OFF_RES);
    unsigned short* cbbf    = (unsigned short*)(ws + OFF_CBBF);
    float*          Aws     = (float*)(ws + OFF_A);
    float*          Bws     = (float*)(ws + OFF_B);
    float*          maxb    = (float*)(ws + OFF_MAXB);
    double*         lossacc = (double*)(ws + OFF_LOSS);
    int*            counts  = (int*)(ws + OFF_CNT);
    int*            idxbuf  = (int*)(ws + OFF_IDX);

    hipMemsetAsync(ws + OFF_LOSS, 0, 32 + NLAYERS * NE * 4, stream);
    pairsum_kernel<<<1024, 256, 0, stream>>>(cb, Bws, cbbf);
    maxb_kernel<<<1, 256, 0, stream>>>(Bws, maxb);

    for (int l = 0; l < NLAYERS; ++l) {
        const float* rin = (l == 0) ? z : res;
        const float* cbl = cb + (size_t)l * NE * EDIM;
        pairsum_kernel<<<8192, 256, 0, stream>>>(rin, Aws, nullptr);
        gemm_dist_kernel<<<2048, 512, 0, stream>>>(rin,
                                                   cbbf + (size_t)l * NE * EDIM,
                                                   Bws + l * NE, drelbase);
        rowscan_kernel<<<8192, 256, 0, stream>>>(rin, res, cbl, drelbase,
                                                 Aws, Bws + l * NE, maxb + l,
                                                 lossacc + l, counts + l * NE,
                                                 idxbuf + l * NROWS);
    }
    zqsum_kernel<<<16384, 256, 0, stream>>>(z, res, outz);
    writeidx_kernel<<<512, 256, 0, stream>>>(idxbuf, idxf);
    finalize_kernel<<<1, 256, 0, stream>>>(lossacc, counts, out, perp);
}